// Round 1
// baseline (893.141 us; speedup 1.0000x reference)
//
#include <hip/hip_runtime.h>
#include <hip/hip_fp16.h>

typedef _Float16 h8 __attribute__((ext_vector_type(8)));
typedef _Float16 h4 __attribute__((ext_vector_type(4)));
typedef _Float16 h2 __attribute__((ext_vector_type(2)));
typedef float f4 __attribute__((ext_vector_type(4)));

#define EMB    300
#define HID    200
#define NR     600     // 3*HID
#define KP     320     // K padded for MFMA (300 -> 10*32)
#define NPAD   1216    // N padded (2*600 -> 76*16)
#define SEQ    512
#define MTOT   16384   // B*S

#if defined(__has_builtin)
#if __has_builtin(__builtin_amdgcn_fdot2)
#define USE_FDOT2 1
#endif
#endif

__device__ __forceinline__ float fdot2f(h2 a, h2 b, float c) {
#ifdef USE_FDOT2
  return __builtin_amdgcn_fdot2(a, b, c, false);
#else
  return c + (float)a[0] * (float)b[0] + (float)a[1] * (float)b[1];
#endif
}

__device__ __forceinline__ float sigm(float x) { return 1.0f / (1.0f + __expf(-x)); }
__device__ __forceinline__ float tanhf_(float x) { return 1.0f - 2.0f / (1.0f + __expf(2.0f * x)); }

// ---------------- prep: convert/pad input-proj weights & biases -------------
__global__ __launch_bounds__(256) void prep_kernel(
    const float* __restrict__ w_ih_f, const float* __restrict__ w_ih_b,
    const float* __restrict__ b_ih_f, const float* __restrict__ b_ih_b,
    _Float16* __restrict__ Wcvt, float* __restrict__ bias_cat) {
  int idx = blockIdx.x * 256 + threadIdx.x;
  if (idx < NPAD * KP) {
    int n = idx / KP, k = idx - n * KP;
    float v = 0.0f;
    if (k < EMB) {
      if (n < NR) v = w_ih_f[n * EMB + k];
      else if (n < 2 * NR) v = w_ih_b[(n - NR) * EMB + k];
    }
    Wcvt[idx] = (_Float16)v;
  }
  if (idx < NPAD) {
    float bv = 0.0f;
    if (idx < NR) bv = b_ih_f[idx];
    else if (idx < 2 * NR) bv = b_ih_b[idx - NR];
    bias_cat[idx] = bv;
  }
}

// ---------------- gi GEMM: gather + [16384,320]x[320,1216] f16 MFMA ---------
// BM=128, 512 threads (8 waves). Wave w: M-subtiles 2*(w&3), 2*(w&3)+1,
// N-half (w>>2) -> 38 N-tiles in 2 chunks of 19.
__global__ __launch_bounds__(512) void gi_gemm(
    const int* __restrict__ text, const float* __restrict__ emb,
    const _Float16* __restrict__ Wcvt, const float* __restrict__ bias_cat,
    __half* __restrict__ gi) {
  __shared__ _Float16 At[128][328];   // +8 halfs pad to break bank conflicts
  const int t = threadIdx.x;
  const int m0 = blockIdx.x * 128;
  {
    const int row = t >> 2;
    const int q = t & 3;
    const int tokid = text[m0 + row];
    const float4* ep = (const float4*)(emb + (size_t)tokid * EMB);
    for (int c4 = q; c4 < 75; c4 += 4) {
      float4 v = ep[c4];
      h4 hv = { (_Float16)v.x, (_Float16)v.y, (_Float16)v.z, (_Float16)v.w };
      *(h4*)&At[row][c4 * 4] = hv;
    }
    for (int c = 300 + q; c < 328; c += 4) At[row][c] = (_Float16)0.0f;
  }
  __syncthreads();

  const int wv = t >> 6, lane = t & 63;
  const int l15 = lane & 15, l4 = lane >> 4;
  const int nhalf = wv >> 2;
  const int ms0 = (wv & 3) * 2;
  const int r0 = ms0 * 16 + l15;
  const int r1 = r0 + 16;

  for (int c2 = 0; c2 < 2; ++c2) {
    const int nbase = nhalf * 38 + c2 * 19;
    f4 acc0[19], acc1[19];
#pragma unroll
    for (int i = 0; i < 19; ++i) { acc0[i] = (f4){0,0,0,0}; acc1[i] = (f4){0,0,0,0}; }
    for (int ks = 0; ks < 10; ++ks) {
      h8 a0 = *(const h8*)&At[r0][ks * 32 + l4 * 8];
      h8 a1 = *(const h8*)&At[r1][ks * 32 + l4 * 8];
#pragma unroll
      for (int i = 0; i < 19; ++i) {
        const h8* bp = (const h8*)(Wcvt + (size_t)((nbase + i) * 16 + l15) * KP + ks * 32 + l4 * 8);
        h8 bf = *bp;
        acc0[i] = __builtin_amdgcn_mfma_f32_16x16x32_f16(a0, bf, acc0[i], 0, 0, 0);
        acc1[i] = __builtin_amdgcn_mfma_f32_16x16x32_f16(a1, bf, acc1[i], 0, 0, 0);
      }
    }
#pragma unroll
    for (int i = 0; i < 19; ++i) {
      const int n = (nbase + i) * 16 + l15;
      const float bv = bias_cat[n];
#pragma unroll
      for (int j = 0; j < 4; ++j) {
        const int mA = m0 + ms0 * 16 + l4 * 4 + j;
        gi[(size_t)mA * NPAD + n] = (__half)(acc0[i][j] + bv);
        gi[(size_t)(mA + 16) * NPAD + n] = (__half)(acc1[i][j] + bv);
      }
    }
  }
}

// ---------------- GRU recurrence: 64 WGs = (dir, batch), weights in VGPRs ---
// 512 threads: t = rg*4 + kg. Thread (rg,kg) holds rows rg*5..rg*5+4,
// k in [kg*50, kg*50+50) as packed f16 pairs. 125 dot2 / thread / step.
__global__ __launch_bounds__(512, 2) void gru_rec(
    const float* __restrict__ w_hh_f, const float* __restrict__ b_hh_f,
    const float* __restrict__ w_hh_b, const float* __restrict__ b_hh_b,
    const float* __restrict__ h0_f,  const float* __restrict__ h0_b,
    const __half* __restrict__ gi, __half* __restrict__ hs) {
  const int t = threadIdx.x;
  const int dir = blockIdx.x >> 5;
  const int b = blockIdx.x & 31;
  const float* w_hh = dir ? w_hh_b : w_hh_f;
  const float* bhh_g = dir ? b_hh_b : b_hh_f;
  const float* h0 = dir ? h0_b : h0_f;

  __shared__ __align__(16) _Float16 h_pad[4 * 64];     // 4 kg regions, 128B-aligned
  __shared__ float h_f[HID];
  __shared__ float y_lds[NR];
  __shared__ float bhh[NR];
  __shared__ __align__(16) _Float16 gi_lds[2][NR + 8]; // double-buffered gi row

  const int rg = t >> 2, kg = t & 3;

  h2 wpk[5][25];
#pragma unroll
  for (int i = 0; i < 5; ++i) {
    const int r = rg * 5 + i;
    const bool valid = (r < NR);
    const float* wr = w_hh + (size_t)(valid ? r : 0) * HID + kg * 50;
#pragma unroll
    for (int kk = 0; kk < 25; ++kk) {
      float w0 = valid ? wr[2 * kk] : 0.0f;
      float w1 = valid ? wr[2 * kk + 1] : 0.0f;
      wpk[i][kk] = (h2){ (_Float16)w0, (_Float16)w1 };
    }
  }

  for (int j = t; j < HID; j += 512) {
    float hv = (h0[b * HID + j] - 0.5f) * (1.0f / (float)HID);
    h_f[j] = hv;
    int p = j >> 1;
    h_pad[(p / 25) * 64 + (p % 25) * 2 + (j & 1)] = (_Float16)hv;
  }
  for (int j = t; j < NR; j += 512) bhh[j] = bhh_g[j];
  {
    const int s0 = dir ? (SEQ - 1) : 0;
    const h2* g0 = (const h2*)(gi + (size_t)(b * SEQ + s0) * NPAD + dir * NR);
    if (t < NR / 2) ((h2*)gi_lds[0])[t] = g0[t];
  }
  __syncthreads();

  const h2* hb = (const h2*)&h_pad[kg * 64];

  for (int st = 0; st < SEQ; ++st) {
    const int s = dir ? (SEQ - 1 - st) : st;
    // 1. issue prefetch of next step's gi row (hidden under GEMV)
    h2 pf = (h2){(_Float16)0.0f, (_Float16)0.0f};
    const bool do_pf = (t < NR / 2) && (st < SEQ - 1);
    if (do_pf) {
      const int sn = dir ? (SEQ - 2 - st) : (st + 1);
      const h2* gn = (const h2*)(gi + (size_t)(b * SEQ + sn) * NPAD + dir * NR);
      pf = gn[t];
    }
    // 2. GEMV: y = W_hh * h   (f16 dot2, f32 accum; 5 independent chains)
    h2 hp[25];
#pragma unroll
    for (int kk = 0; kk < 25; ++kk) hp[kk] = hb[kk];
    float a0 = 0, a1 = 0, a2 = 0, a3 = 0, a4 = 0;
#pragma unroll
    for (int kk = 0; kk < 25; ++kk) {
      a0 = fdot2f(wpk[0][kk], hp[kk], a0);
      a1 = fdot2f(wpk[1][kk], hp[kk], a1);
      a2 = fdot2f(wpk[2][kk], hp[kk], a2);
      a3 = fdot2f(wpk[3][kk], hp[kk], a3);
      a4 = fdot2f(wpk[4][kk], hp[kk], a4);
    }
    // 3. reduce across the 4 k-groups (adjacent lanes)
    a0 += __shfl_xor(a0, 1); a0 += __shfl_xor(a0, 2);
    a1 += __shfl_xor(a1, 1); a1 += __shfl_xor(a1, 2);
    a2 += __shfl_xor(a2, 1); a2 += __shfl_xor(a2, 2);
    a3 += __shfl_xor(a3, 1); a3 += __shfl_xor(a3, 2);
    a4 += __shfl_xor(a4, 1); a4 += __shfl_xor(a4, 2);
    if (kg == 0 && rg < 120) {
      const int r = rg * 5;
      y_lds[r] = a0; y_lds[r + 1] = a1; y_lds[r + 2] = a2;
      y_lds[r + 3] = a3; y_lds[r + 4] = a4;
    }
    __syncthreads();
    // 4. gates + state update (PyTorch GRUCell order r,z,n; b_hh inside r*( ))
    if (t < HID) {
      const _Float16* gih = gi_lds[st & 1];
      const float ir = (float)gih[t];
      const float iz = (float)gih[HID + t];
      const float inn = (float)gih[2 * HID + t];
      const float yr = y_lds[t] + bhh[t];
      const float yz = y_lds[HID + t] + bhh[HID + t];
      const float yn = y_lds[2 * HID + t] + bhh[2 * HID + t];
      const float r = sigm(ir + yr);
      const float z = sigm(iz + yz);
      const float n = tanhf_(inn + r * yn);
      const float hnew = (1.0f - z) * n + z * h_f[t];
      h_f[t] = hnew;
      const int p = t >> 1;
      h_pad[(p / 25) * 64 + (p % 25) * 2 + (t & 1)] = (_Float16)hnew;
      hs[(size_t)(b * SEQ + s) * 400 + dir * HID + t] = (__half)hnew;
    }
    // 5. land prefetched gi row into the other buffer
    if (do_pf) ((h2*)gi_lds[(st + 1) & 1])[t] = pf;
    __syncthreads();
  }
}

// ---------------- final linear: [16384,400] x [400,10] ---------------------
__global__ __launch_bounds__(256) void final_linear(
    const __half* __restrict__ hs, const float* __restrict__ lin_w,
    const float* __restrict__ lin_b, float* __restrict__ out) {
  __shared__ _Float16 hsl[64][400];
  __shared__ _Float16 lwl[10][400];
  const int t = threadIdx.x;
  const int m0 = blockIdx.x * 64;
  const ushort4* hp = (const ushort4*)(hs + (size_t)m0 * 400);
  for (int idx = t; idx < 64 * 100; idx += 256) {
    ushort4 v = hp[idx];
    const int row = idx / 100, c = idx - row * 100;
    *(ushort4*)&hsl[row][c * 4] = v;
  }
  for (int idx = t; idx < 10 * 400; idx += 256) {
    (&lwl[0][0])[idx] = (_Float16)lin_w[idx];
  }
  __syncthreads();
  for (int idx = t; idx < 640; idx += 256) {
    const int m = idx / 10, c = idx - (idx / 10) * 10;
    const h2* hr = (const h2*)hsl[m];
    const h2* wr = (const h2*)lwl[c];
    float acc = 0.0f;
#pragma unroll 8
    for (int kk = 0; kk < 200; ++kk) acc = fdot2f(hr[kk], wr[kk], acc);
    out[(size_t)(m0 + m) * 10 + c] = acc + lin_b[c];
  }
}

extern "C" void kernel_launch(void* const* d_in, const int* in_sizes, int n_in,
                              void* d_out, int out_size, void* d_ws, size_t ws_size,
                              hipStream_t stream) {
  const int*   text   = (const int*)d_in[0];
  const float* emb    = (const float*)d_in[1];
  const float* w_ih_f = (const float*)d_in[2];
  const float* w_hh_f = (const float*)d_in[3];
  const float* b_ih_f = (const float*)d_in[4];
  const float* b_hh_f = (const float*)d_in[5];
  const float* w_ih_b = (const float*)d_in[6];
  const float* w_hh_b = (const float*)d_in[7];
  const float* b_ih_b = (const float*)d_in[8];
  const float* b_hh_b = (const float*)d_in[9];
  const float* lin_w  = (const float*)d_in[10];
  const float* lin_b  = (const float*)d_in[11];
  const float* h0_f   = (const float*)d_in[12];
  const float* h0_b   = (const float*)d_in[13];
  float* out = (float*)d_out;

  char* ws = (char*)d_ws;
  _Float16* Wcvt     = (_Float16*)(ws);                 // 778,240 B
  float*    bias_cat = (float*)(ws + 778240);           //   4,864 B
  __half*   gi       = (__half*)(ws + 783360);          // 39,845,888 B
  __half*   hs       = (__half*)(ws + 40629248);        // 13,107,200 B  (end ~53.7MB)

  prep_kernel<<<dim3((NPAD * KP + 255) / 256), dim3(256), 0, stream>>>(
      w_ih_f, w_ih_b, b_ih_f, b_ih_b, Wcvt, bias_cat);
  gi_gemm<<<dim3(MTOT / 128), dim3(512), 0, stream>>>(
      text, emb, Wcvt, bias_cat, gi);
  gru_rec<<<dim3(64), dim3(512), 0, stream>>>(
      w_hh_f, b_hh_f, w_hh_b, b_hh_b, h0_f, h0_b, gi, hs);
  final_linear<<<dim3(MTOT / 64), dim3(256), 0, stream>>>(
      hs, lin_w, lin_b, out);
}